// Round 10
// baseline (703.737 us; speedup 1.0000x reference)
//
#include <hip/hip_runtime.h>

namespace {

constexpr int kS = 1024;
constexpr int kD = 64;
constexpr int kH = 128;

typedef __attribute__((ext_vector_type(2))) _Float16 half2v;
typedef __attribute__((ext_vector_type(4))) float f32x4;
typedef __attribute__((ext_vector_type(8))) _Float16 half8;

__device__ __forceinline__ float fdot2(unsigned w, unsigned h, float acc) {
#if __has_builtin(__builtin_amdgcn_fdot2)
  return __builtin_amdgcn_fdot2(__builtin_bit_cast(half2v, w),
                                __builtin_bit_cast(half2v, h), acc, false);
#else
  float d;
  asm("v_dot2_f32_f16 %0, %1, %2, %3" : "=v"(d) : "v"(w), "v"(h), "v"(acc));
  return d;
#endif
}

// broadcast lane k's packed h-dword to all lanes, result in VGPR
__device__ __forceinline__ unsigned bcast(unsigned v, int k) {
  return (unsigned)__builtin_amdgcn_ds_bpermute(4 * k, (int)v);
}

// RNE f16 pack (cvt_pkrtz is RTZ -> systematic shrink bias over 1024 steps)
__device__ __forceinline__ unsigned pk16(float a, float b) {
  half2v h;
  h.x = (_Float16)a;
  h.y = (_Float16)b;
  return __builtin_bit_cast(unsigned, h);
}

__device__ __forceinline__ float fast_tanh(float x) {
#if __has_builtin(__builtin_amdgcn_fmed3f)
  x = __builtin_amdgcn_fmed3f(x, -15.f, 15.f);  // single-instr clamp
#else
  x = fminf(fmaxf(x, -15.f), 15.f);
#endif
  float e = __expf(2.f * x);
  return (e - 1.f) * __builtin_amdgcn_rcpf(e + 1.f);
}

#if __has_builtin(__builtin_amdgcn_mov_dpp)
__device__ __forceinline__ float lane_xor1(float v) {
  return __int_as_float(__builtin_amdgcn_mov_dpp(__float_as_int(v), 0xB1, 0xF, 0xF, true));
}
#else
__device__ __forceinline__ float lane_xor1(float v) {
  return __int_as_float(__builtin_amdgcn_ds_swizzle(__float_as_int(v), 0x041F));
}
#endif

// async global->LDS: 8 x 16B/lane = one 8 KB xp chunk (no VGPR round-trip)
__device__ __forceinline__ void stage_chunk(const char* g, unsigned* lds, int L) {
#pragma unroll
  for (int k = 0; k < 8; ++k) {
    __builtin_amdgcn_global_load_lds(
        (const __attribute__((address_space(1))) void*)(g + k * 1024 + L * 16),
        (__attribute__((address_space(3))) void*)(lds + k * 256), 16, 0, 0);
  }
}

// owner lane of canonical h-dword d under the ownership map L=16a+2t+e ->
// dword 8t+2a+e  (t=(L>>1)&7, a=L>>4, e=L&1). Inverse: t=d>>3, a=(d&7)>>1, e=d&1.
__host__ __device__ constexpr int owner_lane(int d) {
  return 16 * ((d & 7) >> 1) + 2 * (d >> 3) + (d & 1);
}

// xp (f16) layout per (dir,b) slab of kS*kH elems, chunk-transposed:
//   idx = (t>>5)*(32*kH) + (t&31)*kH + j     (dir=1 pre-time-reversed)
// -> one 32-step chunk = 8 KB contiguous, DMA-stageable.

// =====================  Phase A: x-projection via f16 MFMA  =====================
// (unchanged: 84 us, correct)
__global__ __launch_bounds__(256, 2) void xproj_kernel(
    const float* __restrict__ inputs,
    const float* __restrict__ Wih_fw, const float* __restrict__ bih_fw,
    const float* __restrict__ bhh_fw,
    const float* __restrict__ Wih_bw, const float* __restrict__ bih_bw,
    const float* __restrict__ bhh_bw,
    _Float16* __restrict__ xp) {
  __shared__ _Float16 Wl[256 * 80];
  __shared__ _Float16 xl[128 * 80];
  __shared__ float biasl[256];

  const int tid = threadIdx.x;
  const int b = blockIdx.x;
  const int w = tid >> 6;
  const int lane = tid & 63;
  const int n16 = lane & 15;
  const int q = lane >> 4;

  {
    const int jd = tid;
    const float* src = (jd < kH) ? (Wih_fw + jd * kD) : (Wih_bw + (jd - kH) * kD);
    const float4* s4 = (const float4*)src;
#pragma unroll
    for (int k = 0; k < 8; ++k) {
      float4 a = s4[2 * k], c = s4[2 * k + 1];
      half8 h;
      h[0] = (_Float16)a.x; h[1] = (_Float16)a.y; h[2] = (_Float16)a.z; h[3] = (_Float16)a.w;
      h[4] = (_Float16)c.x; h[5] = (_Float16)c.y; h[6] = (_Float16)c.z; h[7] = (_Float16)c.w;
      *(half8*)&Wl[jd * 80 + k * 8] = h;
    }
    biasl[jd] = (jd < kH) ? (bih_fw[jd] + bhh_fw[jd])
                          : (bih_bw[jd - kH] + bhh_bw[jd - kH]);
  }

  for (int ch = 0; ch < 8; ++ch) {
    __syncthreads();
    {
      const int tl = tid >> 1, hf = tid & 1;
      const float4* s4 = (const float4*)(inputs +
          ((size_t)b * kS + ch * 128 + tl) * kD + hf * 32);
#pragma unroll
      for (int k = 0; k < 4; ++k) {
        float4 a = s4[2 * k], c = s4[2 * k + 1];
        half8 h;
        h[0] = (_Float16)a.x; h[1] = (_Float16)a.y; h[2] = (_Float16)a.z; h[3] = (_Float16)a.w;
        h[4] = (_Float16)c.x; h[5] = (_Float16)c.y; h[6] = (_Float16)c.z; h[7] = (_Float16)c.w;
        *(half8*)&xl[tl * 80 + hf * 32 + k * 8] = h;
      }
    }
    __syncthreads();

    half8 bf0[4], bf1[4];
    float bs[4];
#pragma unroll
    for (int nn = 0; nn < 4; ++nn) {
      const int jd = (w * 4 + nn) * 16 + n16;
      bf0[nn] = *(const half8*)&Wl[jd * 80 + q * 8];
      bf1[nn] = *(const half8*)&Wl[jd * 80 + q * 8 + 32];
      bs[nn] = biasl[jd];
    }

#pragma unroll 2
    for (int m = 0; m < 8; ++m) {
      const int trow = m * 16 + n16;
      const half8 a0 = *(const half8*)&xl[trow * 80 + q * 8];
      const half8 a1 = *(const half8*)&xl[trow * 80 + q * 8 + 32];
#pragma unroll
      for (int nn = 0; nn < 4; ++nn) {
        f32x4 acc = {0.f, 0.f, 0.f, 0.f};
        acc = __builtin_amdgcn_mfma_f32_16x16x32_f16(a0, bf0[nn], acc, 0, 0, 0);
        acc = __builtin_amdgcn_mfma_f32_16x16x32_f16(a1, bf1[nn], acc, 0, 0, 0);
        const int jd = (w * 4 + nn) * 16 + n16;
        const int dir = jd >> 7, j = jd & 127;
        const size_t slab = (size_t)(dir * 256 + b) * (kS * kH);
#pragma unroll
        for (int r = 0; r < 4; ++r) {
          const int t = ch * 128 + m * 16 + q * 4 + r;
          const int tt = dir ? (kS - 1 - t) : t;
          xp[slab + (size_t)(tt >> 5) * (32 * kH) + (tt & 31) * kH + j] =
              (_Float16)(acc[r] + bs[nn]);
        }
      }
    }
  }
}

// =====================  Phase B: dual-pipe recurrence (MFMA k<64, VALU k>=64) ====
// 512 blocks x 64 threads (ONE wave): dir = blockIdx>>8, b = blockIdx&255.
// Ownership (matches MFMA C layout): lane L = 16a+2t+e owns units u0=16t+4a+2e,
// u0+1 = canonical h-dword dL = 8t+2a+e. Per step:
//   k=0..63  : 16 MFMA (8 M-tiles x 2 K-tiles), B = h replicated across cols,
//              B-frags = 2 lane-addressed ds_read_b128 from jrn[prev].
//              Lane's C pair = rows 4a+2e, +1 of tile t -> 30-cndmask select.
//   k=64..127: 32 bpermute (canonical dwords 32..63, owner-permuted index)
//              + 64 fdot2 on the VALU.  [R9 bug: only 32..47 were covered]
// Matrix pipe (~320cy) runs concurrently with the ~700cy VALU issue stream.
__global__ __launch_bounds__(64, 1) void birnn_step_kernel(
    const _Float16* __restrict__ xp,
    const float* __restrict__ Whh_fw, const float* __restrict__ Whh_bw,
    const float* __restrict__ fcW, const float* __restrict__ fcb,
    float* __restrict__ out) {
  const int dir = blockIdx.x >> 8;
  const int b = blockIdx.x & 255;
  const int L = threadIdx.x;
  const int n16 = L & 15;
  const int q = L >> 4;          // a
  const int t8 = (L >> 1) & 7;   // owned tile
  const int e = L & 1;
  const int dL = 8 * t8 + 2 * q + e;  // owned canonical dword
  const int u0 = 2 * dL;              // owned units u0, u0+1

  __shared__ unsigned jrn[32 * 68];   // h ring + fc journal (canonical dwords)
  __shared__ unsigned xbuf[2][2048];  // two 8 KB xp chunks
  __shared__ unsigned fcwl[64];       // fc weights, packed f16 pairs
  __shared__ float outbuf[kS];

  const float* __restrict__ Whh = dir ? Whh_bw : Whh_fw;

  // ---- A-fragments (k=0..63): Whh[16*jm + n16][32*tk + 8q .. +7] (64 VGPRs)
  half8 Afr[8][2];
#pragma unroll
  for (int jm = 0; jm < 8; ++jm) {
#pragma unroll
    for (int tk = 0; tk < 2; ++tk) {
      const float* src = Whh + (size_t)(16 * jm + n16) * kH + 32 * tk + 8 * q;
      const float4 a = *(const float4*)src;
      const float4 c = *(const float4*)(src + 4);
      half8 h;
      h[0] = (_Float16)a.x; h[1] = (_Float16)a.y; h[2] = (_Float16)a.z; h[3] = (_Float16)a.w;
      h[4] = (_Float16)c.x; h[5] = (_Float16)c.y; h[6] = (_Float16)c.z; h[7] = (_Float16)c.w;
      Afr[jm][tk] = h;
    }
  }
  // ---- VALU weights (k=64..127) for owned rows u0, u0+1 (64 VGPRs)
  unsigned w0v[32], w1v[32];
  {
    const float* r0 = Whh + (size_t)u0 * kH + 64;
    const float* r1 = Whh + (size_t)(u0 + 1) * kH + 64;
#pragma unroll
    for (int g = 0; g < 32; ++g) {
      w0v[g] = pk16(r0[2 * g], r0[2 * g + 1]);
      w1v[g] = pk16(r1[2 * g], r1[2 * g + 1]);
    }
  }
  fcwl[L] = pk16(fcW[dir * kH + 2 * L], fcW[dir * kH + 2 * L + 1]);
  jrn[31 * 68 + L] = 0;  // h_{-1} = 0 (all 64 dwords of row 31)

  unsigned hcur = 0;  // owned packed pair (h[u0], h[u0+1])
  const f32x4 zeroq = {0.f, 0.f, 0.f, 0.f};

  // ---- prime xp chunks 0,1 ----
  const char* slab = (const char*)(xp + (size_t)(dir * 256 + b) * (kS * kH));
  stage_chunk(slab, &xbuf[0][0], L);
  stage_chunk(slab + 8192, &xbuf[1][0], L);
  asm volatile("s_waitcnt vmcnt(0)" ::: "memory");

  for (int c = 0; c < 32; ++c) {
    const unsigned* xb = &xbuf[c & 1][0];

    for (int s = 0; s < 32; ++s) {
      const int prev = (s + 31) & 31;
      // ---- B-frags (issue first; DS in-order after prev step's jrn write) ----
      const uint4 B0 = *(const uint4*)&jrn[prev * 68 + 4 * q];        // dwords 4q..+3
      const uint4 B1 = *(const uint4*)&jrn[prev * 68 + 16 + 4 * q];   // dwords 16+4q..
      // ---- bperm broadcast of canonical dwords 32..63 (owner-permuted) ----
      unsigned hb[32];
#pragma unroll
      for (int g = 0; g < 32; ++g) hb[g] = bcast(hcur, owner_lane(32 + g));
      const unsigned xdw = xb[s * 64 + dL];  // (x[u0], x[u1]) packed

      // ---- MFMA: k = 0..63, 8 M-tiles x 2 K-tiles ----
      const half8 b0f = __builtin_bit_cast(half8, B0);
      const half8 b1f = __builtin_bit_cast(half8, B1);
      f32x4 Cacc[8];
#pragma unroll
      for (int jm = 0; jm < 8; ++jm)
        Cacc[jm] = __builtin_amdgcn_mfma_f32_16x16x32_f16(Afr[jm][0], b0f, zeroq, 0, 0, 0);
#pragma unroll
      for (int jm = 0; jm < 8; ++jm)
        Cacc[jm] = __builtin_amdgcn_mfma_f32_16x16x32_f16(Afr[jm][1], b1f, Cacc[jm], 0, 0, 0);

      // ---- VALU dots: k = 64..127 for owned rows (full 32 dwords) ----
      float a0 = 0.f, a1 = 0.f, c0 = 0.f, c1 = 0.f;
#pragma unroll
      for (int g = 0; g < 16; ++g) {
        a0 = fdot2(w0v[g], hb[g], a0);
        c0 = fdot2(w1v[g], hb[g], c0);
        a1 = fdot2(w0v[16 + g], hb[16 + g], a1);
        c1 = fdot2(w1v[16 + g], hb[16 + g], c1);
      }

      // ---- static select of this lane's C pair: tile t8, rows 4q+2e, +1 ----
      const f32x4 T01 = (t8 & 1) ? Cacc[1] : Cacc[0];
      const f32x4 T23 = (t8 & 1) ? Cacc[3] : Cacc[2];
      const f32x4 T45 = (t8 & 1) ? Cacc[5] : Cacc[4];
      const f32x4 T67 = (t8 & 1) ? Cacc[7] : Cacc[6];
      const f32x4 U0 = (t8 & 2) ? T23 : T01;
      const f32x4 U1 = (t8 & 2) ? T67 : T45;
      const f32x4 Q = (t8 & 4) ? U1 : U0;
      const float s0 = e ? Q[2] : Q[0];
      const float s1 = e ? Q[3] : Q[1];

      const half2v xh = __builtin_bit_cast(half2v, xdw);
      const float va = s0 + (a0 + a1) + (float)xh.x;
      const float vb = s1 + (c0 + c1) + (float)xh.y;
      hcur = pk16(fast_tanh(va), fast_tanh(vb));
      jrn[s * 68 + dL] = hcur;  // canonical position; broadcast source for s+1
    }

    // ---- fc drain of chunk c (canonical rows; unchanged) ----
    {
      const int tl = L >> 1, jh = L & 1;
      const uint4* rp = (const uint4*)&jrn[tl * 68 + jh * 32];
      const uint4* fp = (const uint4*)&fcwl[jh * 32];
      float acc = 0.f;
#pragma unroll
      for (int k = 0; k < 8; ++k) {
        const uint4 hv = rp[k];
        const uint4 fw = fp[k];
        acc = fdot2(fw.x, hv.x, acc);
        acc = fdot2(fw.y, hv.y, acc);
        acc = fdot2(fw.z, hv.z, acc);
        acc = fdot2(fw.w, hv.w, acc);
      }
      acc += lane_xor1(acc);
      if (jh == 0) outbuf[c * 32 + tl] = acc;
    }

    // ---- stage chunk c+2 into the buffer just freed; gate chunk c+1 ----
    if (c < 30) {
      stage_chunk(slab + (size_t)(c + 2) * 8192, &xbuf[c & 1][0], L);
      asm volatile("s_waitcnt vmcnt(8)" ::: "memory");
    } else if (c == 30) {
      asm volatile("s_waitcnt vmcnt(0)" ::: "memory");
    }
  }

  // ---- emit: one atomic pass (fw adds fcb) ----
  const float fcb0 = (dir == 0) ? fcb[0] : 0.f;
#pragma unroll
  for (int k = 0; k < 16; ++k) {
    const int t = L + 64 * k;
    const int td = dir ? (kS - 1 - t) : t;
    atomicAdd(&out[(size_t)b * kS + td], outbuf[t] + fcb0);
  }
}

}  // namespace

extern "C" void kernel_launch(void* const* d_in, const int* in_sizes, int n_in,
                              void* d_out, int out_size, void* d_ws, size_t ws_size,
                              hipStream_t stream) {
  (void)in_sizes; (void)n_in; (void)ws_size;
  const float* inputs = (const float*)d_in[0];
  const float* Wih_fw = (const float*)d_in[1];
  const float* Whh_fw = (const float*)d_in[2];
  const float* bih_fw = (const float*)d_in[3];
  const float* bhh_fw = (const float*)d_in[4];
  const float* Wih_bw = (const float*)d_in[5];
  const float* Whh_bw = (const float*)d_in[6];
  const float* bih_bw = (const float*)d_in[7];
  const float* bhh_bw = (const float*)d_in[8];
  const float* fc_W   = (const float*)d_in[9];
  const float* fc_b   = (const float*)d_in[10];
  float* out = (float*)d_out;
  _Float16* xpw = (_Float16*)d_ws;  // 2*256*1024*128 f16 = 128 MiB

  hipMemsetAsync(out, 0, (size_t)out_size * sizeof(float), stream);

  hipLaunchKernelGGL(xproj_kernel, dim3(256), dim3(256), 0, stream,
                     inputs, Wih_fw, bih_fw, bhh_fw, Wih_bw, bih_bw, bhh_bw, xpw);
  hipLaunchKernelGGL(birnn_step_kernel, dim3(512), dim3(64), 0, stream,
                     xpw, Whh_fw, Whh_bw, fc_W, fc_b, out);
}

// Round 11
// 566.726 us; speedup vs baseline: 1.2418x; 1.2418x over previous
//
#include <hip/hip_runtime.h>

namespace {

constexpr int kS = 1024;
constexpr int kD = 64;
constexpr int kH = 128;

typedef __attribute__((ext_vector_type(2))) _Float16 half2v;
typedef __attribute__((ext_vector_type(4))) float f32x4;
typedef __attribute__((ext_vector_type(8))) _Float16 half8;

__device__ __forceinline__ float fdot2(unsigned w, unsigned h, float acc) {
#if __has_builtin(__builtin_amdgcn_fdot2)
  return __builtin_amdgcn_fdot2(__builtin_bit_cast(half2v, w),
                                __builtin_bit_cast(half2v, h), acc, false);
#else
  float d;
  asm("v_dot2_f32_f16 %0, %1, %2, %3" : "=v"(d) : "v"(w), "v"(h), "v"(acc));
  return d;
#endif
}

// broadcast lane k's packed h-dword to all lanes, result in VGPR
__device__ __forceinline__ unsigned bcast(unsigned v, int k) {
  return (unsigned)__builtin_amdgcn_ds_bpermute(4 * k, (int)v);
}

// RNE f16 pack (cvt_pkrtz is RTZ -> systematic shrink bias over 1024 steps)
__device__ __forceinline__ unsigned pk16(float a, float b) {
  half2v h;
  h.x = (_Float16)a;
  h.y = (_Float16)b;
  return __builtin_bit_cast(unsigned, h);
}

__device__ __forceinline__ half8 to_h8(float4 a, float4 c) {
  half8 h;
  h[0] = (_Float16)a.x; h[1] = (_Float16)a.y; h[2] = (_Float16)a.z; h[3] = (_Float16)a.w;
  h[4] = (_Float16)c.x; h[5] = (_Float16)c.y; h[6] = (_Float16)c.z; h[7] = (_Float16)c.w;
  return h;
}

__device__ __forceinline__ float fast_tanh(float x) {
#if __has_builtin(__builtin_amdgcn_fmed3f)
  x = __builtin_amdgcn_fmed3f(x, -15.f, 15.f);  // single-instr clamp
#else
  x = fminf(fmaxf(x, -15.f), 15.f);
#endif
  float e = __expf(2.f * x);
  return (e - 1.f) * __builtin_amdgcn_rcpf(e + 1.f);
}

#if __has_builtin(__builtin_amdgcn_mov_dpp)
__device__ __forceinline__ float lane_xor1(float v) {
  return __int_as_float(__builtin_amdgcn_mov_dpp(__float_as_int(v), 0xB1, 0xF, 0xF, true));
}
#else
__device__ __forceinline__ float lane_xor1(float v) {
  return __int_as_float(__builtin_amdgcn_ds_swizzle(__float_as_int(v), 0x041F));
}
#endif

// async global->LDS: 8 x 16B/lane = one 8 KB chunk (no VGPR round-trip)
__device__ __forceinline__ void stage_chunk(const char* g, unsigned* lds, int L) {
#pragma unroll
  for (int k = 0; k < 8; ++k) {
    __builtin_amdgcn_global_load_lds(
        (const __attribute__((address_space(1))) void*)(g + k * 1024 + L * 16),
        (__attribute__((address_space(3))) void*)(lds + k * 256), 16, 0, 0);
  }
}

// =====================  Fused BiRNN: xproj-on-matrix-pipe + R7 recurrence  ======
// 512 blocks x 64 threads (ONE wave): dir = blockIdx>>8, b = blockIdx&255.
// Per 32-step chunk: DMA the raw inputs chunk (32 t x 64 D f32 = 8 KB,
// contiguous for both directions), then compute x = inputs*Wih^T + (bias at
// read) via 32 mfma_f32_16x16x32_f16 using the VERIFIED xproj fragment layout:
//   A = Wih  (M dim = j): AW[m][tk] = Wih[16m+n16][32tk+8q..+7], persistent.
//   B = inputs (N dim = t): Bf[n][tk] = staged[r_loc][32tk+8q..+7],
//       r_loc = dir ? 31-(16n+n16) : 16n+n16  (time reversal at build).
//   C quad (m,n): rows j=16m+4q+r, col t=16n+n16 -> pk16 pairs ->
//       ds_write_b64 at xcomp[t*68 + 8m+2q]  (same packed layout R7 reads).
// Step loop is R7-identical (64 bpermute + 128 fdot2, jrn journal, fc drain),
// except x-read adds bias regs bj0/bj1. No xp workspace, no second kernel.
__global__ __launch_bounds__(64, 1) void birnn_fused_kernel(
    const float* __restrict__ inputs,
    const float* __restrict__ Wih_fw, const float* __restrict__ bih_fw,
    const float* __restrict__ bhh_fw,
    const float* __restrict__ Wih_bw, const float* __restrict__ bih_bw,
    const float* __restrict__ bhh_bw,
    const float* __restrict__ Whh_fw, const float* __restrict__ Whh_bw,
    const float* __restrict__ fcW, const float* __restrict__ fcb,
    float* __restrict__ out) {
  const int dir = blockIdx.x >> 8;
  const int b = blockIdx.x & 255;
  const int L = threadIdx.x;
  const int n16 = L & 15;
  const int q = L >> 4;

  __shared__ float instage[2][2048];  // two staged 8 KB inputs chunks (f32)
  __shared__ unsigned xcomp[32 * 68]; // computed x, packed f16 pairs, 68-dw rows
  __shared__ unsigned jrn[32 * 68];   // h ring + fc journal
  __shared__ unsigned fcwl[64];       // fc weights, packed f16 pairs
  __shared__ float outbuf[kS];

  const float* __restrict__ Whh = dir ? Whh_bw : Whh_fw;
  const float* __restrict__ Wih = dir ? Wih_bw : Wih_fw;
  const float* __restrict__ bihd = dir ? bih_bw : bih_fw;
  const float* __restrict__ bhhd = dir ? bhh_bw : bhh_fw;

  // ---- Whh weights: rows j0=2L, j1=2L+1 -> 128 packed-f16 dwords ----
  unsigned w0[64], w1[64];
  {
    const float* r0 = Whh + (size_t)(2 * L) * kH;
    const float* r1 = Whh + (size_t)(2 * L + 1) * kH;
#pragma unroll
    for (int k = 0; k < 64; ++k) {
      w0[k] = pk16(r0[2 * k], r0[2 * k + 1]);
      w1[k] = pk16(r1[2 * k], r1[2 * k + 1]);
    }
  }
  // ---- Wih A-fragments (persistent): AW[m][tk] ----
  half8 AW[8][2];
#pragma unroll
  for (int m = 0; m < 8; ++m) {
#pragma unroll
    for (int tk = 0; tk < 2; ++tk) {
      const float* src = Wih + (size_t)(16 * m + n16) * kD + 32 * tk + 8 * q;
      AW[m][tk] = to_h8(*(const float4*)src, *(const float4*)(src + 4));
    }
  }
  const float bj0 = bihd[2 * L] + bhhd[2 * L];
  const float bj1 = bihd[2 * L + 1] + bhhd[2 * L + 1];
  fcwl[L] = pk16(fcW[dir * kH + 2 * L], fcW[dir * kH + 2 * L + 1]);

  unsigned hcur = 0;  // h_{-1} = 0 (lane-local packed pair)
  const f32x4 zeroq = {0.f, 0.f, 0.f, 0.f};

  // ---- x-projection for one staged chunk: 4 B-frags, 32 MFMA, 16 b64 writes ----
  auto buildx = [&](const float* stg) {
    half8 Bf[2][2];
#pragma unroll
    for (int n = 0; n < 2; ++n) {
      const int r_loc = dir ? (31 - (16 * n + n16)) : (16 * n + n16);
      const float* rp = stg + r_loc * 64;
#pragma unroll
      for (int tk = 0; tk < 2; ++tk) {
        const float* p = rp + 32 * tk + 8 * q;
        Bf[n][tk] = to_h8(*(const float4*)p, *(const float4*)(p + 4));
      }
    }
#pragma unroll
    for (int n = 0; n < 2; ++n) {
      const int t_loc = 16 * n + n16;
      unsigned* wbase = &xcomp[t_loc * 68];
#pragma unroll
      for (int m = 0; m < 8; ++m) {
        f32x4 Cq = __builtin_amdgcn_mfma_f32_16x16x32_f16(AW[m][0], Bf[n][0], zeroq, 0, 0, 0);
        Cq = __builtin_amdgcn_mfma_f32_16x16x32_f16(AW[m][1], Bf[n][1], Cq, 0, 0, 0);
        uint2 pw;
        pw.x = pk16(Cq[0], Cq[1]);  // j = 16m+4q, 16m+4q+1
        pw.y = pk16(Cq[2], Cq[3]);  // j = 16m+4q+2, +3
        *(uint2*)(wbase + 8 * m + 2 * q) = pw;
      }
    }
  };

  // ---- staging: raw inputs chunks (contiguous both dirs; reversal in buildx) ----
  const char* islab = (const char*)(inputs + (size_t)b * kS * kD);
  const int c0off = dir ? 992 : 0;  // global row of chunk c: dir ? 992-32c : 32c
  stage_chunk(islab + (size_t)(dir ? (c0off - 0) : 0) * 256, (unsigned*)&instage[0][0], L);
  stage_chunk(islab + (size_t)(dir ? (c0off - 32) : 32) * 256, (unsigned*)&instage[1][0], L);
  asm volatile("s_waitcnt vmcnt(8)" ::: "memory");  // chunk 0 staged
  buildx(&instage[0][0]);

  for (int c = 0; c < 32; ++c) {
    // ---- 32 recurrence steps on xcomp (R7-identical core) ----
#pragma unroll 2
    for (int s = 0; s < 32; ++s) {
      const unsigned xdw = xcomp[s * 68 + L];  // packed (x[2L], x[2L+1])
      float a0 = 0.f, a1 = 0.f, c0 = 0.f, c1 = 0.f;

      unsigned hb[32];
#pragma unroll
      for (int k = 0; k < 32; ++k) hb[k] = bcast(hcur, k);
#pragma unroll
      for (int k = 0; k < 32; ++k) {
        a0 = fdot2(w0[k], hb[k], a0);
        c0 = fdot2(w1[k], hb[k], c0);
      }
#pragma unroll
      for (int k = 0; k < 32; ++k) hb[k] = bcast(hcur, 32 + k);
#pragma unroll
      for (int k = 0; k < 32; ++k) {
        a1 = fdot2(w0[32 + k], hb[k], a1);
        c1 = fdot2(w1[32 + k], hb[k], c1);
      }

      const half2v xh = __builtin_bit_cast(half2v, xdw);
      const float va = (a0 + a1) + ((float)xh.x + bj0);
      const float vb = (c0 + c1) + ((float)xh.y + bj1);
      hcur = pk16(fast_tanh(va), fast_tanh(vb));
      jrn[s * 68 + L] = hcur;  // journal only; read at fc drain
    }

    // ---- fc drain of chunk c ----
    {
      const int tl = L >> 1, jh = L & 1;
      const uint4* rp = (const uint4*)&jrn[tl * 68 + jh * 32];
      const uint4* fp = (const uint4*)&fcwl[jh * 32];
      float acc = 0.f;
#pragma unroll
      for (int k = 0; k < 8; ++k) {
        const uint4 hv = rp[k];
        const uint4 fw = fp[k];
        acc = fdot2(fw.x, hv.x, acc);
        acc = fdot2(fw.y, hv.y, acc);
        acc = fdot2(fw.z, hv.z, acc);
        acc = fdot2(fw.w, hv.w, acc);
      }
      acc += lane_xor1(acc);
      if (jh == 0) outbuf[c * 32 + tl] = acc;
    }

    // ---- stage chunk c+2 into freed buffer; gate c+1; build its xcomp ----
    if (c < 30) {
      const int g2 = dir ? (c0off - 32 * (c + 2)) : 32 * (c + 2);
      stage_chunk(islab + (size_t)g2 * 256, (unsigned*)&instage[c & 1][0], L);
      asm volatile("s_waitcnt vmcnt(8)" ::: "memory");  // chunk c+1 resident
      buildx(&instage[(c + 1) & 1][0]);
    } else if (c == 30) {
      asm volatile("s_waitcnt vmcnt(0)" ::: "memory");
      buildx(&instage[1][0]);
    }
  }

  // ---- emit: one atomic pass (fw adds fcb) ----
  const float fcb0 = (dir == 0) ? fcb[0] : 0.f;
#pragma unroll
  for (int k = 0; k < 16; ++k) {
    const int t = L + 64 * k;
    const int td = dir ? (kS - 1 - t) : t;
    atomicAdd(&out[(size_t)b * kS + td], outbuf[t] + fcb0);
  }
}

}  // namespace

extern "C" void kernel_launch(void* const* d_in, const int* in_sizes, int n_in,
                              void* d_out, int out_size, void* d_ws, size_t ws_size,
                              hipStream_t stream) {
  (void)in_sizes; (void)n_in; (void)d_ws; (void)ws_size;
  const float* inputs = (const float*)d_in[0];
  const float* Wih_fw = (const float*)d_in[1];
  const float* Whh_fw = (const float*)d_in[2];
  const float* bih_fw = (const float*)d_in[3];
  const float* bhh_fw = (const float*)d_in[4];
  const float* Wih_bw = (const float*)d_in[5];
  const float* Whh_bw = (const float*)d_in[6];
  const float* bih_bw = (const float*)d_in[7];
  const float* bhh_bw = (const float*)d_in[8];
  const float* fc_W   = (const float*)d_in[9];
  const float* fc_b   = (const float*)d_in[10];
  float* out = (float*)d_out;

  hipMemsetAsync(out, 0, (size_t)out_size * sizeof(float), stream);

  hipLaunchKernelGGL(birnn_fused_kernel, dim3(512), dim3(64), 0, stream,
                     inputs, Wih_fw, bih_fw, bhh_fw, Wih_bw, bih_bw, bhh_bw,
                     Whh_fw, Whh_bw, fc_W, fc_b, out);
}